// Round 1
// baseline (54.299 us; speedup 1.0000x reference)
//
#include <hip/hip_runtime.h>

// YGate, D=2, S=1, INDEX=[0], L=13, N=8192.
// M = (Z@X)/1j = Pauli Y = [[0,-i],[i,0]] acting on the MSB axis (stride H=4096).
// out_re[k] =  x_im[k+H]  (k<H),   -x_im[k-H]  (k>=H)
// out_im[k] = -x_re[k+H]  (k<H),    x_re[k-H]  (k>=H)
// d_out = [re(8192) | im(8192)] floats.

__global__ __launch_bounds__(256) void ygate_kernel(
    const float4* __restrict__ xre,
    const float4* __restrict__ xim,
    float4* __restrict__ out)
{
    const int t = blockIdx.x * blockDim.x + threadIdx.x;  // 0..2047 (float4 index over 8192 floats)
    const int H4 = 1024;   // 4096 floats / 4
    const int N4 = 2048;   // 8192 floats / 4

    float4 r, i, re_o, im_o;
    if (t < H4) {
        // partner index t + H4
        r = xre[t + H4];
        i = xim[t + H4];
        re_o = i;
        im_o = make_float4(-r.x, -r.y, -r.z, -r.w);
    } else {
        // partner index t - H4
        r = xre[t - H4];
        i = xim[t - H4];
        re_o = make_float4(-i.x, -i.y, -i.z, -i.w);
        im_o = r;
    }
    out[t]      = re_o;   // real part block
    out[N4 + t] = im_o;   // imag part block
}

extern "C" void kernel_launch(void* const* d_in, const int* in_sizes, int n_in,
                              void* d_out, int out_size, void* d_ws, size_t ws_size,
                              hipStream_t stream)
{
    const float4* xre = (const float4*)d_in[0];  // x_re, 8192 floats
    const float4* xim = (const float4*)d_in[1];  // x_im, 8192 floats
    float4* out = (float4*)d_out;                // 16384 floats = [re | im]

    // 2048 float4 work items -> 8 blocks x 256 threads
    ygate_kernel<<<8, 256, 0, stream>>>(xre, xim, out);
}

// Round 2
// 54.180 us; speedup vs baseline: 1.0022x; 1.0022x over previous
//
#include <hip/hip_runtime.h>

// YGate, D=2, S=1, INDEX=[0], L=13, N=8192.
// M = Pauli Y = [[0,-i],[i,0]] on the MSB axis (stride H=4096 floats).
//   t <  H: out_re[t] =  x_im[t+H], out_im[t] = -x_re[t+H]
//   t >= H: out_re[t] = -x_im[t-H], out_im[t] =  x_re[t-H]
// Branch-free: p = t ^ H4 (float4 index), s = +1 for t<H4 else -1:
//   out_re = s * x_im[p];  out_im = -s * x_re[p]
// d_out = [re(8192) | im(8192)] floats. Total traffic 128 KB -> pure
// latency/dispatch-floor regime; timed number is dominated by harness
// ws-poison (40 us, 256 MB fill) outside kernel control.

__global__ __launch_bounds__(128) void ygate_kernel(
    const float4* __restrict__ xre,
    const float4* __restrict__ xim,
    float4* __restrict__ out)
{
    const int t  = blockIdx.x * blockDim.x + threadIdx.x;  // 0..2047
    const int H4 = 1024;   // 4096 floats / 4
    const int N4 = 2048;   // 8192 floats / 4

    const int   p = t ^ H4;                      // partner float4 index
    const float s = (t < H4) ? 1.0f : -1.0f;     // wave-uniform sign

    const float4 r = xre[p];
    const float4 i = xim[p];

    out[t]      = make_float4( s * i.x,  s * i.y,  s * i.z,  s * i.w);
    out[N4 + t] = make_float4(-s * r.x, -s * r.y, -s * r.z, -s * r.w);
}

extern "C" void kernel_launch(void* const* d_in, const int* in_sizes, int n_in,
                              void* d_out, int out_size, void* d_ws, size_t ws_size,
                              hipStream_t stream)
{
    const float4* xre = (const float4*)d_in[0];  // x_re, 8192 floats
    const float4* xim = (const float4*)d_in[1];  // x_im, 8192 floats
    float4* out = (float4*)d_out;                // 16384 floats = [re | im]

    // 2048 float4 work items -> 16 blocks x 128 threads (more CUs, fewer
    // waves each; latency-tuned, though dispatch floor dominates anyway)
    ygate_kernel<<<16, 128, 0, stream>>>(xre, xim, out);
}